// Round 10
// baseline (292.852 us; speedup 1.0000x reference)
//
#include <hip/hip_runtime.h>
#include <hip/hip_bf16.h>
#include <stdint.h>

#define N_NODES 100000
#define DEG 16
#define D_IN 128
#define D_OUT 256
#define K_TOP 32
#define K_CAT 256   // concatenated K = D_IN(self) + D_IN(neigh)

typedef __attribute__((ext_vector_type(8))) short short8;
typedef __attribute__((ext_vector_type(4))) float floatx4;

__device__ __forceinline__ unsigned pack_bf16_rne(float f) {
    union { float f; unsigned u; } c; c.f = f;
    unsigned u = c.u;
    return (u + 0x7fffu + ((u >> 16) & 1u)) >> 16;   // round-to-nearest-even
}
__device__ __forceinline__ float bf16lo_to_f(unsigned lo16) {
    union { unsigned u; float f; } c; c.u = lo16 << 16; return c.f;
}

// async global->LDS, 16B per lane; LDS dest is wave-uniform base + lane*16
typedef __attribute__((address_space(1))) void as1_void;
typedef __attribute__((address_space(3))) void as3_void;
__device__ __forceinline__ void gload_lds16(const void* g, void* l) {
    __builtin_amdgcn_global_load_lds((as1_void*)g, (as3_void*)l, 16, 0, 0);
}

// ---- kernel 1 (merged prep): densify topk -> xbf | feat -> fbf | pack weights ----
#define DB 1563   // ceil(N/64) densify blocks; blocks [DB, DB+256) pack bmat
#define DROWS 64
__global__ __launch_bounds__(256) void k_prep(const float* __restrict__ topk_v,
                                              const int* __restrict__ topk_i,
                                              const float* __restrict__ feat,
                                              const float* __restrict__ w_self,
                                              const float* __restrict__ w_neigh,
                                              unsigned short* __restrict__ xbf,
                                              unsigned short* __restrict__ fbf,
                                              unsigned short* __restrict__ bmat) {
    __shared__ float sx[DROWS * D_IN];   // 32 KiB (densify branch only)
    const int t = threadIdx.x;
    if (blockIdx.x >= DB) {
        // pack [w_self | w_neigh] -> bf16 B[256][256]
        const int o = blockIdx.x - DB;   // 0..255
        float v = (t < D_IN) ? w_self[o * D_IN + t] : w_neigh[o * D_IN + (t - D_IN)];
        bmat[o * K_CAT + t] = (unsigned short)pack_bf16_rne(v);
        return;
    }
    const int row0 = blockIdx.x * DROWS;

    // zero LDS: 8192 floats / 256 thr = 8 float4 per thread
    #pragma unroll
    for (int p = 0; p < 8; ++p)
        *(floatx4*)&sx[(t + p * 256) * 4] = (floatx4){0.f, 0.f, 0.f, 0.f};
    __syncthreads();

    // scatter: 64 rows x 32 pairs = 2048 pairs, 8 per thread, coalesced reads
    const size_t tbase = (size_t)row0 * K_TOP;
    #pragma unroll
    for (int p = 0; p < 8; ++p) {
        int q = t + p * 256;             // 0..2047
        int r = q >> 5;                  // 0..63
        if (row0 + r < N_NODES) {
            int   ci = topk_i[tbase + q];
            float cv = topk_v[tbase + q];
            atomicAdd(&sx[r * D_IN + ci], cv);   // ds_add_f32, no return
        }
    }
    __syncthreads();

    // pack x -> bf16, coalesced: 4096 dwords, 16 per thread
    #pragma unroll
    for (int p = 0; p < 16; ++p) {
        int d = t + p * 256;             // dword index 0..4095
        int r = d >> 6;                  // 0..63
        int c2 = (d & 63) * 2;
        if (row0 + r < N_NODES) {
            float2 v = *(const float2*)&sx[r * D_IN + c2];
            ((unsigned*)(xbf + (size_t)(row0 + r) * D_IN))[d & 63] =
                pack_bf16_rne(v.x) | (pack_bf16_rne(v.y) << 16);
        }
    }

    // feat -> bf16 into fbf (stride 128): 2048 float4, 8 per thread
    #pragma unroll
    for (int p = 0; p < 8; ++p) {
        int q = t + p * 256;             // 0..2047
        int r = q >> 5;                  // 0..63
        int c4 = (q & 31) * 4;
        if (row0 + r < N_NODES) {
            float4 f = *(const float4*)(feat + (size_t)(row0 + r) * D_IN + c4);
            uint2 pk;
            pk.x = pack_bf16_rne(f.x) | (pack_bf16_rne(f.y) << 16);
            pk.y = pack_bf16_rne(f.z) | (pack_bf16_rne(f.w) << 16);
            ((uint2*)(fbf + (size_t)(row0 + r) * D_IN))[q & 31] = pk;
        }
    }
}

// ------ kernel 2 (fused): per-block SpMM gather -> LDS agg, then GEMM over K=256 -------
// out[N][256] = [fbf | agg] @ B[256][256]^T + bias.
// Phase 1: r9's pipelined gather (quarter-wave per row, ping-pong vva/vvb).
// Phase 2: BM=128, BN=256, BK=32, 8 waves (2x4), swapped-operand mfma.
// NEW vs r9: NO Bs LDS tile — B fragments load directly from bmat (128 KB,
// L2-resident). LDS 80K -> 48K => 3 blocks/CU (24 waves). Barriers only after
// kt 0..2 (As dbuf staging); kt 3..7 barrier-free.
#define BM 128
#define BN 256
#define BK 32
#define NTA 4   // K-steps covered by fbf
#define NT  8

__global__ __launch_bounds__(512, 2) void k_fused(const float* __restrict__ csr_w,
                                                  const int* __restrict__ col_idx,
                                                  const unsigned short* __restrict__ xbf,
                                                  const unsigned short* __restrict__ fbf,
                                                  const unsigned short* __restrict__ bmat,
                                                  const float* __restrict__ bias,
                                                  float* __restrict__ out) {
    __shared__ __align__(16) unsigned short Agg[BM * 128];     // 32 KiB, swizzled
    __shared__ __align__(16) unsigned short As[2][BM * BK];    // 16 KiB
    const int t    = threadIdx.x;
    const int lane = t & 63, wave = t >> 6;
    const int l16  = lane & 15, quad = lane >> 4;
    const int row0 = blockIdx.x * BM;

    // A staging geometry: each wave's 64 lanes cover 16 rows x 4x16B chunks (linear LDS)
    const int a_r = wave * 16 + (lane >> 2);
    const int a_c = (lane & 3) * 8;                          // shorts
    int a_gr = row0 + a_r; if (a_gr >= N_NODES) a_gr = N_NODES - 1;  // clamp: garbage
    const unsigned short* gA = fbf + (size_t)a_gr * D_IN + a_c;      // rows never stored

#define STAGE_A(buf, tt) gload_lds16(gA + (tt) * BK, &As[buf][wave * 16 * BK])

    // issue first A K-step now; it flies during the gather phase
    STAGE_A(0, 0);

    // ---- phase 1: pipelined gather-aggregate, quarter-wave per row, 4 passes ----
    const int ql = lane & 15, qb = lane & 48;
    const int qrow = wave * 4 + (lane >> 4);                 // quarter's row within a pass

    // hoist all 4 passes' col/weight (coalesced, guarded)
    int cc[4]; float ww[4];
    #pragma unroll
    for (int p = 0; p < 4; ++p) {
        const int gr = row0 + p * 32 + qrow;
        cc[p] = 0; ww[p] = 0.f;
        if (gr < N_NODES) {
            cc[p] = __builtin_nontemporal_load(col_idx + (size_t)gr * DEG + ql);
            ww[p] = __builtin_nontemporal_load(csr_w   + (size_t)gr * DEG + ql);
        }
    }

    uint4 vva[8], vvb[8];
    // prime: sub-pass 0 = pass 0, edges 0..7
    #pragma unroll
    for (int e = 0; e < 8; ++e) {
        int col = __shfl(cc[0], qb | e);
        vva[e] = *(const uint4*)(xbf + (size_t)col * D_IN + ql * 8);
    }
    float a[8] = {0.f, 0.f, 0.f, 0.f, 0.f, 0.f, 0.f, 0.f};

    #pragma unroll
    for (int s = 0; s < 8; ++s) {                            // 8 sub-passes (4 passes x 2)
        const int p  = s >> 1;
        const int e0 = (s & 1) * 8;
        // issue next sub-pass's 8 gathers into the other buffer (static selection)
        if (s < 7) {
            const int np  = (s + 1) >> 1;
            const int ne0 = ((s + 1) & 1) * 8;
            #pragma unroll
            for (int e = 0; e < 8; ++e) {
                int col = __shfl(cc[np], qb | (ne0 + e));
                if (s & 1) vva[e] = *(const uint4*)(xbf + (size_t)col * D_IN + ql * 8);
                else       vvb[e] = *(const uint4*)(xbf + (size_t)col * D_IN + ql * 8);
            }
        }
        // consume current buffer
        #pragma unroll
        for (int e = 0; e < 8; ++e) {
            float we = __shfl(ww[p], qb | (e0 + e));
            uint4 v = (s & 1) ? vvb[e] : vva[e];
            a[0] += we * bf16lo_to_f(v.x & 0xffffu);
            a[1] += we * bf16lo_to_f(v.x >> 16);
            a[2] += we * bf16lo_to_f(v.y & 0xffffu);
            a[3] += we * bf16lo_to_f(v.y >> 16);
            a[4] += we * bf16lo_to_f(v.z & 0xffffu);
            a[5] += we * bf16lo_to_f(v.z >> 16);
            a[6] += we * bf16lo_to_f(v.w & 0xffffu);
            a[7] += we * bf16lo_to_f(v.w >> 16);
        }
        if (s & 1) {
            // end of pass p: pack this row to Agg (XOR-swizzled), reset accumulator
            const int r = p * 32 + qrow;
            uint4 pk;
            pk.x = pack_bf16_rne(a[0]) | (pack_bf16_rne(a[1]) << 16);
            pk.y = pack_bf16_rne(a[2]) | (pack_bf16_rne(a[3]) << 16);
            pk.z = pack_bf16_rne(a[4]) | (pack_bf16_rne(a[5]) << 16);
            pk.w = pack_bf16_rne(a[6]) | (pack_bf16_rne(a[7]) << 16);
            *(uint4*)&Agg[r * 128 + ((ql * 8) ^ ((r & 7) << 3))] = pk;
            #pragma unroll
            for (int z = 0; z < 8; ++z) a[z] = 0.f;
        }
    }

    // ---- phase 2: GEMM K-loop; B fragments straight from L2-resident bmat ----
    const int wr = wave >> 2, wc = wave & 3;                 // 2x4 wave grid, 64x64 each
    const unsigned short* gBw = bmat + (size_t)(wc * 64 + l16) * K_CAT + quad * 8;
    floatx4 acc[4][4];
    #pragma unroll
    for (int i = 0; i < 4; ++i)
        #pragma unroll
        for (int j = 0; j < 4; ++j)
            acc[i][j] = (floatx4){0.f, 0.f, 0.f, 0.f};

    __syncthreads();   // drains vmcnt(0): As[0] staged + Agg writes visible

    #pragma unroll
    for (int tt = 0; tt < NT; ++tt) {
        const int cur = tt & 1;
        if (tt + 1 < NTA) STAGE_A(cur ^ 1, tt + 1);          // prefetch next A (fbf half)

        short8 afr[4], bfr[4];
        #pragma unroll
        for (int j = 0; j < 4; ++j)                          // 16B per lane, 64B segments
            bfr[j] = *(const short8*)(gBw + (size_t)j * 16 * K_CAT + tt * BK);
        if (tt < NTA) {
            #pragma unroll
            for (int i = 0; i < 4; ++i)
                afr[i] = *(const short8*)&As[cur][(wr * 64 + i * 16 + l16) * BK + quad * 8];
        } else {
            const int c0 = (tt - NTA) * 32 + quad * 8;
            #pragma unroll
            for (int i = 0; i < 4; ++i) {
                const int m = wr * 64 + i * 16 + l16;
                afr[i] = *(const short8*)&Agg[m * 128 + (c0 ^ ((m & 7) << 3))];
            }
        }

        #pragma unroll
        for (int i = 0; i < 4; ++i)
            #pragma unroll
            for (int j = 0; j < 4; ++j)   // swapped: out-rows <- afr lanes, out-cols <- bfr regs
                acc[i][j] = __builtin_amdgcn_mfma_f32_16x16x32_bf16(bfr[j], afr[i], acc[i][j], 0, 0, 0);

        if (tt + 1 < NTA) __syncthreads();                   // only while As dbuf in use
    }

    // epilogue: lane holds row m = l16 (+16i+64wr), cols quad*4..+3 (+16j+64wc)
    // nontemporal floatx4 stores (write-once stream stays out of L2/L3)
    #pragma unroll
    for (int j = 0; j < 4; ++j) {
        const int cg = wc * 64 + j * 16 + quad * 4;
        const floatx4 bv = *(const floatx4*)&bias[cg];
        #pragma unroll
        for (int i = 0; i < 4; ++i) {
            const int gr = row0 + wr * 64 + i * 16 + l16;
            if (gr < N_NODES) {
                floatx4 v = acc[i][j] + bv;
                __builtin_nontemporal_store(v, (floatx4*)(out + (size_t)gr * D_OUT + cg));
            }
        }
    }
#undef STAGE_A
}

extern "C" void kernel_launch(void* const* d_in, const int* in_sizes, int n_in,
                              void* d_out, int out_size, void* d_ws, size_t ws_size,
                              hipStream_t stream) {
    const float* feat    = (const float*)d_in[0];
    const float* topk_v  = (const float*)d_in[1];
    const float* csr_w   = (const float*)d_in[2];
    const float* w_neigh = (const float*)d_in[3];
    const float* w_self  = (const float*)d_in[4];
    const float* b_self  = (const float*)d_in[5];
    const int*   topk_i  = (const int*)d_in[6];
    // d_in[7] = indptr (fixed degree 16, unused), d_in[8] = indices
    const int*   indices = (const int*)d_in[8];
    float* out = (float*)d_out;

    // workspace layout (bf16): x[N*128] | f[N*128] | B[256*256]  (~51.4 MB)
    unsigned short* xbf  = (unsigned short*)d_ws;
    unsigned short* fbf  = xbf + (size_t)N_NODES * D_IN;
    unsigned short* bmat = fbf + (size_t)N_NODES * D_IN;

    k_prep<<<dim3(DB + 256), dim3(256), 0, stream>>>(
        topk_v, topk_i, feat, w_self, w_neigh, xbf, fbf, bmat);
    k_fused<<<dim3((N_NODES + BM - 1) / BM), dim3(512), 0, stream>>>(
        csr_w, indices, xbf, fbf, bmat, b_self, out);
}